// Round 11
// baseline (325.182 us; speedup 1.0000x reference)
//
#include <hip/hip_runtime.h>
#include <stdint.h>

typedef __attribute__((ext_vector_type(4))) float  f32x4;
typedef __attribute__((ext_vector_type(4))) int    i32x4;
typedef __attribute__((ext_vector_type(8))) __bf16 bf16x8;

constexpr int M_DIM = 8192, N_DIM = 4096, K_DIM = 4096;

#define VMCNT(n)   asm volatile("s_waitcnt vmcnt(" #n ")" ::: "memory")
#define SB __builtin_amdgcn_sched_barrier(0)
#define SGV_LOAD(dst, ptr) \
  asm volatile("global_load_dword %0, %1, off" : "=v"(dst) : "v"(ptr) : "memory")

// ======================= pass 1: fused prep ================================
constexpr int PX_BLOCKS = M_DIM;                            // one block per x-row
constexpr int PW_BLOCKS = (N_DIM * K_DIM / 2) / (8 * 256);  // 4096 (8 ints/thread)
constexpr int PO_BLOCKS = N_DIM / 256;                      // 16

__global__ __launch_bounds__(256) void prep(
    const float* __restrict__ X, const int* __restrict__ P,
    const float* __restrict__ S, const float* __restrict__ O,
    char* __restrict__ qx, char* __restrict__ qw,
    char* __restrict__ qR, char* __restrict__ qo,
    float* __restrict__ sx, float* __restrict__ sR,
    float* __restrict__ so, float* __restrict__ ST) {
  const int b = blockIdx.x;
  const int tid = threadIdx.x;
  if (b < PX_BLOCKS) {
    // ---- x row: rowmax -> sx, qx int8; group sums -> sR, qR ----
    __shared__ float red[256];
    __shared__ float gsum[32];
    __shared__ float sr_sh;
    const int m = b;
    const float* xr = X + (size_t)m * K_DIM + tid * 16;
    f32x4 v[4];
#pragma unroll
    for (int j = 0; j < 4; ++j) v[j] = *(const f32x4*)(xr + 4 * j);
    float mx = 0.f, sm = 0.f;
#pragma unroll
    for (int j = 0; j < 4; ++j)
#pragma unroll
      for (int e = 0; e < 4; ++e) { float t = v[j][e]; mx = fmaxf(mx, fabsf(t)); sm += t; }
    red[tid] = mx;
    float s8 = sm;
    s8 += __shfl_down(s8, 4, 8);
    s8 += __shfl_down(s8, 2, 8);
    s8 += __shfl_down(s8, 1, 8);
    if ((tid & 7) == 0) gsum[tid >> 3] = s8;   // 16 elems/thread, 8 thr/group(128)
    __syncthreads();
    for (int s = 128; s > 0; s >>= 1) {
      if (tid < s) red[tid] = fmaxf(red[tid], red[tid + s]);
      __syncthreads();
    }
    const float sxv = fmaxf(red[0], 1e-20f) * (1.f / 127.f);
    if (tid == 0) {
      sx[m] = sxv;
      float rm = 0.f;
      for (int g = 0; g < 32; ++g) rm = fmaxf(rm, fabsf(gsum[g]));
      float sr = fmaxf(rm, 1e-20f) * (1.f / 127.f);
      sR[m] = sr;
      sr_sh = sr;
    }
    __syncthreads();
    const float inv = 1.f / sxv;
    int pk[4];
#pragma unroll
    for (int j = 0; j < 4; ++j) {
      int b0 = ((int)rintf(v[j][0] * inv)) & 255;
      int b1 = ((int)rintf(v[j][1] * inv)) & 255;
      int b2 = ((int)rintf(v[j][2] * inv)) & 255;
      int b3 = ((int)rintf(v[j][3] * inv)) & 255;
      pk[j] = b0 | (b1 << 8) | (b2 << 16) | (b3 << 24);
    }
    *(i32x4*)(qx + (size_t)m * K_DIM + tid * 16) = (i32x4){pk[0], pk[1], pk[2], pk[3]};
    if (tid < 64) {
      char qv = 0;
      if (tid < 32) qv = (char)(int)rintf(gsum[tid] / sr_sh);
      qR[(size_t)m * 64 + tid] = qv;   // zero-padded 32..63
    }
  } else if (b < PX_BLOCKS + PW_BLOCKS) {
    // ---- unpack int4 nibbles -> int8 (exact) ----
    // each packed int32 holds ONE byte = 2 nibbles = 2 consecutive weights.
    size_t i = (size_t)(b - PX_BLOCKS) * 256 + tid;   // 8 ints = 16 weights
    const i32x4* src = (const i32x4*)P + i * 2;
    i32x4 p0 = src[0], p1 = src[1];
    int o0 = (p0[0] & 15) | (((p0[0] >> 4) & 15) << 8) |
             ((p0[1] & 15) << 16) | (((p0[1] >> 4) & 15) << 24);
    int o1 = (p0[2] & 15) | (((p0[2] >> 4) & 15) << 8) |
             ((p0[3] & 15) << 16) | (((p0[3] >> 4) & 15) << 24);
    int o2 = (p1[0] & 15) | (((p1[0] >> 4) & 15) << 8) |
             ((p1[1] & 15) << 16) | (((p1[1] >> 4) & 15) << 24);
    int o3 = (p1[2] & 15) | (((p1[2] >> 4) & 15) << 8) |
             ((p1[3] & 15) << 16) | (((p1[3] >> 4) & 15) << 24);
    *(i32x4*)(qw + i * 16) = (i32x4){o0, o1, o2, o3};
  } else {
    // ---- per-n: offsets -> so,qo ; scales -> ST transpose ----
    const int n = (b - PX_BLOCKS - PW_BLOCKS) * 256 + tid;
    float ov[32];
    float om = 0.f;
#pragma unroll
    for (int g = 0; g < 32; ++g) { ov[g] = O[n * 32 + g]; om = fmaxf(om, fabsf(ov[g])); }
    const float sov = fmaxf(om, 1e-20f) * (1.f / 127.f);
    so[n] = sov;
    const float invo = 1.f / sov;
    int qb[16];
#pragma unroll
    for (int j = 0; j < 8; ++j) {
      int b0 = ((int)rintf(ov[4 * j + 0] * invo)) & 255;
      int b1 = ((int)rintf(ov[4 * j + 1] * invo)) & 255;
      int b2 = ((int)rintf(ov[4 * j + 2] * invo)) & 255;
      int b3 = ((int)rintf(ov[4 * j + 3] * invo)) & 255;
      qb[j] = b0 | (b1 << 8) | (b2 << 16) | (b3 << 24);
    }
#pragma unroll
    for (int j = 8; j < 16; ++j) qb[j] = 0;
#pragma unroll
    for (int j = 0; j < 4; ++j)
      *(i32x4*)(qo + (size_t)n * 64 + j * 16) =
          (i32x4){qb[4 * j], qb[4 * j + 1], qb[4 * j + 2], qb[4 * j + 3]};
#pragma unroll
    for (int g = 0; g < 32; ++g) ST[(size_t)g * N_DIM + n] = S[n * 32 + g];
  }
}

// ======================= pass 2: int8 GEMM =================================
// stage one 128-row x 64-col int8 chunk (8 KiB). LDS linear; source col
// pre-XOR-swizzled (rule #21): c ^= ((r>>1)&3)<<4  -> 2-way (free) on read.
__device__ __forceinline__ void stage128(const char* g, char* l, int tid) {
  const int r = tid >> 2;
  const int c = ((tid & 3) * 16) ^ (((r >> 1) & 3) << 4);
  __builtin_amdgcn_global_load_lds(
      (const __attribute__((address_space(1))) uint32_t*)(g + (size_t)r * K_DIM + c),
      (__attribute__((address_space(3))) uint32_t*)(l + (tid >> 6) * 1024),
      16, 0, 0);
}

__device__ __forceinline__ void read_a8(i32x4 (&dst)[4], const char* Ab,
                                        int wm, int ln15, int lq, int mh) {
#pragma unroll
  for (int m4 = 0; m4 < 4; ++m4) {
    const int r = wm * 128 + (mh * 4 + m4) * 16 + ln15;
    dst[m4] = *(const i32x4*)(Ab + r * 64 + ((lq * 16) ^ (((r >> 1) & 3) << 4)));
  }
}

__device__ __forceinline__ void read_b8(i32x4 (&dst)[4], const char* Bb,
                                        int wn, int ln15, int lq) {
#pragma unroll
  for (int n = 0; n < 4; ++n) {
    const int r = wn * 64 + n * 16 + ln15;
    dst[n] = *(const i32x4*)(Bb + r * 64 + ((lq * 16) ^ (((r >> 1) & 3) << 4)));
  }
}

// 16 i8-MFMA (K=64) + per-tile group-scale accumulate into f32
__device__ __forceinline__ void mfma_cvt(f32x4 (&acc)[8][4], const i32x4 (&af)[4],
                                         const i32x4 (&bf)[4], const float (&sgv)[4],
                                         int mb) {
  const i32x4 Z = (i32x4){0, 0, 0, 0};
  __builtin_amdgcn_s_setprio(1);
#pragma unroll
  for (int m4 = 0; m4 < 4; ++m4) {
    i32x4 P0 = __builtin_amdgcn_mfma_i32_16x16x64_i8(af[m4], bf[0], Z, 0, 0, 0);
    i32x4 P1 = __builtin_amdgcn_mfma_i32_16x16x64_i8(af[m4], bf[1], Z, 0, 0, 0);
    i32x4 P2 = __builtin_amdgcn_mfma_i32_16x16x64_i8(af[m4], bf[2], Z, 0, 0, 0);
    i32x4 P3 = __builtin_amdgcn_mfma_i32_16x16x64_i8(af[m4], bf[3], Z, 0, 0, 0);
    f32x4 f0, f1, f2, f3;
#pragma unroll
    for (int r = 0; r < 4; ++r) {
      f0[r] = (float)P0[r]; f1[r] = (float)P1[r];
      f2[r] = (float)P2[r]; f3[r] = (float)P3[r];
    }
    acc[mb + m4][0] += sgv[0] * f0;
    acc[mb + m4][1] += sgv[1] * f1;
    acc[mb + m4][2] += sgv[2] * f2;
    acc[mb + m4][3] += sgv[3] * f3;
  }
  __builtin_amdgcn_s_setprio(0);
}

__global__ __launch_bounds__(512, 2) void gemm_i8(
    const char* __restrict__ qx, const char* __restrict__ qw,
    const float* __restrict__ ST, const float* __restrict__ sx,
    const float* __restrict__ sR, const float* __restrict__ so,
    const char* __restrict__ qR, const char* __restrict__ qo,
    const float* __restrict__ Bias, float* __restrict__ Y) {
  extern __shared__ char lds[];  // A b0|A b1|B b0|B b1 = 4 x 16 KiB

  const int tid  = threadIdx.x;
  const int lane = tid & 63;
  const int wid  = tid >> 6;
  const int wm   = wid >> 2;
  const int wn   = wid & 3;
  const int ln15 = lane & 15;
  const int lq   = lane >> 4;

  // T1: bijective XCD swizzle (nwg = 512)
  const int id  = blockIdx.y * gridDim.x + blockIdx.x;
  const int swz = (id & 7) * 64 + (id >> 3);
  const int bn0 = (swz & 15) * 256;
  const int bm0 = (swz >> 4) * 256;

  const char* Ag = qx + (size_t)bm0 * K_DIM;
  const char* Bg = qw + (size_t)bn0 * K_DIM;
  char* Ab0 = lds;
  char* Ab1 = lds + 16384;
  char* Bb0 = lds + 32768;
  char* Bb1 = lds + 49152;

  f32x4 acc[8][4];
#pragma unroll
  for (int m = 0; m < 8; ++m)
#pragma unroll
    for (int n = 0; n < 4; ++n)
      acc[m][n] = (f32x4){0.f, 0.f, 0.f, 0.f};

  i32x4 af0[4], af1[4], bfr[4];
  float sgvA[4], sgvB[4];

  // ---- prologue: sgv(g0), tile0 (B,A), B(t=1) ----
#pragma unroll
  for (int n = 0; n < 4; ++n) {
    const float* p = ST + (bn0 + wn * 64 + n * 16 + ln15);
    SGV_LOAD(sgvA[n], p);
  }
  stage128(Bg,                         Bb0, tid);
  stage128(Bg + (size_t)128 * K_DIM,   Bb0 + 8192, tid);
  stage128(Ag,                         Ab0, tid);
  stage128(Ag + (size_t)128 * K_DIM,   Ab0 + 8192, tid);
  stage128(Bg + 64,                       Bb1, tid);
  stage128(Bg + (size_t)128 * K_DIM + 64, Bb1 + 8192, tid);
  VMCNT(2);   // confirm sgvA + tile0; B(1) flies
  __builtin_amdgcn_s_barrier();
  SB;
  read_b8(bfr, Bb0, wn, ln15, lq);
  read_a8(af0, Ab0, wm, ln15, lq, 0);
  SB;

  for (int g = 0; g < 32; ++g) {
    const int t0 = 2 * g;
    const char* gA1 = Ag + (size_t)(t0 + 1) * 64;  // k-offsets (bytes)
    const char* gA2 = Ag + (size_t)(t0 + 2) * 64;
    const char* gB2 = Bg + (size_t)(t0 + 2) * 64;
    const char* gB3 = Bg + (size_t)(t0 + 3) * 64;
    const bool more = (g < 31);

    // ============ tile t0 (even, bufs 0) ============
    // q0: MFMA(mh0); stage A(t0+1); sgv(g+1); read af1(t0)
    mfma_cvt(acc, af0, bfr, sgvA, 0);
    SB;
    stage128(gA1,                       Ab1, tid);
    stage128(gA1 + (size_t)128 * K_DIM, Ab1 + 8192, tid);
    if (more) {
#pragma unroll
      for (int n = 0; n < 4; ++n) {
        const float* p = ST + (size_t)(g + 1) * N_DIM + (bn0 + wn * 64 + n * 16 + ln15);
        SGV_LOAD(sgvB[n], p);
      }
    }
    read_a8(af1, Ab0, wm, ln15, lq, 1);
    SB;
    __builtin_amdgcn_s_barrier();
    SB;
    // q1: MFMA(mh1); stage B(t0+2); confirm t0+1; read t0+1 frags
    mfma_cvt(acc, af1, bfr, sgvA, 4);
    SB;
    if (more) {
      stage128(gB2,                       Bb0, tid);
      stage128(gB2 + (size_t)128 * K_DIM, Bb0 + 8192, tid);
      VMCNT(6);       // confirm B(t0+1)+A(t0+1); sgvB+B(t0+2) fly
    } else {
      VMCNT(0);       // last group: drain (tile 63 operands confirmed)
    }
    __builtin_amdgcn_s_barrier();
    SB;
    read_b8(bfr, Bb1, wn, ln15, lq);
    read_a8(af0, Ab1, wm, ln15, lq, 0);
    SB;

    // ============ tile t1 (odd, bufs 1) ============
    // q0: MFMA(mh0); stage A(t0+2); read af1(t1)
    mfma_cvt(acc, af0, bfr, sgvA, 0);
    SB;
    if (more) {
      stage128(gA2,                       Ab0, tid);
      stage128(gA2 + (size_t)128 * K_DIM, Ab0 + 8192, tid);
    }
    read_a8(af1, Ab1, wm, ln15, lq, 1);
    SB;
    __builtin_amdgcn_s_barrier();
    SB;
    // q1: MFMA(mh1); stage B(t0+3); confirm sgvB + t0+2; read t0+2 frags
    mfma_cvt(acc, af1, bfr, sgvA, 4);
    SB;
    if (more) {
      stage128(gB3,                       Bb1, tid);
      stage128(gB3 + (size_t)128 * K_DIM, Bb1 + 8192, tid);
      VMCNT(2);       // confirm sgvB+B(t0+2)+A(t0+2); B(t0+3) flies
      __builtin_amdgcn_s_barrier();
      SB;
      read_b8(bfr, Bb0, wn, ln15, lq);
      read_a8(af0, Ab0, wm, ln15, lq, 0);
#pragma unroll
      for (int n = 0; n < 4; ++n) sgvA[n] = sgvB[n];
      SB;
    }
  }

  // ---- epilogue: y = sx*acc + sR*so*(qR.qo) + bias ----
  const i32x4 Z = (i32x4){0, 0, 0, 0};
  i32x4 qof[4];
  float sov[4], bv[4];
#pragma unroll
  for (int n = 0; n < 4; ++n) {
    const int col = bn0 + wn * 64 + n * 16 + ln15;
    qof[n] = *(const i32x4*)(qo + (size_t)col * 64 + lq * 16);
    sov[n] = so[col];
    bv[n]  = Bias[col];
  }
#pragma unroll
  for (int m = 0; m < 8; ++m) {
    const int rowb = bm0 + wm * 128 + m * 16;
    i32x4 qrf = *(const i32x4*)(qR + (size_t)(rowb + ln15) * 64 + lq * 16);
    float sxv[4], sRv[4];
#pragma unroll
    for (int r = 0; r < 4; ++r) {
      const int row = rowb + lq * 4 + r;
      sxv[r] = sx[row];
      sRv[r] = sR[row];
    }
#pragma unroll
    for (int n = 0; n < 4; ++n) {
      i32x4 Pe = __builtin_amdgcn_mfma_i32_16x16x64_i8(qrf, qof[n], Z, 0, 0, 0);
      const int col = bn0 + wn * 64 + n * 16 + ln15;
#pragma unroll
      for (int r = 0; r < 4; ++r) {
        const int row = rowb + lq * 4 + r;
        Y[(size_t)row * N_DIM + col] =
            sxv[r] * acc[m][n][r] + sRv[r] * sov[n] * (float)Pe[r] + bv[n];
      }
    }
  }
}

// ------------------- fallback: round-0 fused bf16 kernel -------------------
__global__ __launch_bounds__(256) void qlin_fused_gemm(
    const float* __restrict__ X, const int* __restrict__ P,
    const float* __restrict__ S, const float* __restrict__ Ofs,
    const float* __restrict__ Bias, float* __restrict__ Y)
{
  constexpr int BM = 128, BN = 128, BK = 64;
  constexpr int NT = K_DIM / BK;
  __shared__ __bf16 As[BM * BK];
  __shared__ __bf16 Bs[BN * BK];
  const int tid  = threadIdx.x;
  const int lane = tid & 63;
  const int wv   = tid >> 6;
  const int wr   = (wv >> 1) * 64;
  const int wc   = (wv & 1) * 64;
  const int bn0 = blockIdx.x * BN;
  const int bm0 = blockIdx.y * BM;
  const int srow  = tid >> 1;
  const int shalf = tid & 1;
  const float* xrow = X + (size_t)(bm0 + srow) * K_DIM + shalf * 32;
  const int*   prow = P + (size_t)(bn0 + srow) * (K_DIM / 2) + shalf * 16;
  const int    gbase = (bn0 + srow) * (K_DIM / 128);
  const int rowb = srow * (BK * 2);
  const int sxor = (srow & 7) << 4;
  const int cbb  = shalf * 64;
  f32x4 areg[8];
  i32x4 breg[4];
  float sc, of;
  f32x4 acc[4][4];
#pragma unroll
  for (int i = 0; i < 4; ++i)
#pragma unroll
    for (int j = 0; j < 4; ++j)
      acc[i][j] = (f32x4){0.f, 0.f, 0.f, 0.f};
#pragma unroll
  for (int i = 0; i < 8; ++i) areg[i] = *(const f32x4*)(xrow + 4 * i);
#pragma unroll
  for (int i = 0; i < 4; ++i) breg[i] = *(const i32x4*)(prow + 4 * i);
  sc = S[gbase];
  of = Ofs[gbase];
  for (int kt = 0; kt < NT; ++kt) {
    __syncthreads();
    {
      char* ab = (char*)As + rowb;
      char* bb = (char*)Bs + rowb;
#pragma unroll
      for (int i = 0; i < 4; ++i) {
        bf16x8 v;
        f32x4 u0 = areg[2 * i], u1 = areg[2 * i + 1];
        v[0] = (__bf16)u0[0]; v[1] = (__bf16)u0[1];
        v[2] = (__bf16)u0[2]; v[3] = (__bf16)u0[3];
        v[4] = (__bf16)u1[0]; v[5] = (__bf16)u1[1];
        v[6] = (__bf16)u1[2]; v[7] = (__bf16)u1[3];
        *(bf16x8*)(ab + ((cbb + 16 * i) ^ sxor)) = v;
      }
#pragma unroll
      for (int i = 0; i < 4; ++i) {
        bf16x8 v;
        i32x4 p = breg[i];
#pragma unroll
        for (int j = 0; j < 4; ++j) {
          int pv = p[j];
          v[2 * j]     = (__bf16)fmaf((float)(pv & 15), sc, of);
          v[2 * j + 1] = (__bf16)fmaf((float)((pv >> 4) & 15), sc, of);
        }
        *(bf16x8*)(bb + ((cbb + 16 * i) ^ sxor)) = v;
      }
    }
    if (kt + 1 < NT) {
      const float* xp = xrow + (kt + 1) * BK;
#pragma unroll
      for (int i = 0; i < 8; ++i) areg[i] = *(const f32x4*)(xp + 4 * i);
      const int* pp = prow + (kt + 1) * (BK / 2);
#pragma unroll
      for (int i = 0; i < 4; ++i) breg[i] = *(const i32x4*)(pp + 4 * i);
      int g = gbase + (kt + 1) / 2;
      sc = S[g]; of = Ofs[g];
    }
    __syncthreads();
#pragma unroll
    for (int ks = 0; ks < 2; ++ks) {
      const int cb = ks * 64 + (lane >> 4) * 16;
      bf16x8 afr[4], bfr2[4];
#pragma unroll
      for (int m = 0; m < 4; ++m) {
        int r = wr + m * 16 + (lane & 15);
        afr[m] = *(const bf16x8*)((const char*)As + r * (BK * 2) + (cb ^ ((r & 7) << 4)));
      }
#pragma unroll
      for (int n = 0; n < 4; ++n) {
        int r = wc + n * 16 + (lane & 15);
        bfr2[n] = *(const bf16x8*)((const char*)Bs + r * (BK * 2) + (cb ^ ((r & 7) << 4)));
      }
#pragma unroll
      for (int m = 0; m < 4; ++m)
#pragma unroll
        for (int n = 0; n < 4; ++n)
          acc[m][n] = __builtin_amdgcn_mfma_f32_16x16x32_bf16(afr[m], bfr2[n], acc[m][n], 0, 0, 0);
    }
  }
#pragma unroll
  for (int n = 0; n < 4; ++n) {
    const int col = bn0 + wc + n * 16 + (lane & 15);
    const float bias = Bias[col];
#pragma unroll
    for (int m = 0; m < 4; ++m) {
      const int row0 = bm0 + wr + m * 16 + (lane >> 4) * 4;
#pragma unroll
      for (int r = 0; r < 4; ++r)
        Y[(size_t)(row0 + r) * N_DIM + col] = acc[m][n][r] + bias;
    }
  }
}

extern "C" void kernel_launch(void* const* d_in, const int* in_sizes, int n_in,
                              void* d_out, int out_size, void* d_ws, size_t ws_size,
                              hipStream_t stream) {
  const float* X    = (const float*)d_in[0];
  const int*   P    = (const int*)d_in[1];
  const float* S    = (const float*)d_in[2];
  const float* Ofs  = (const float*)d_in[3];
  const float* Bias = (const float*)d_in[4];
  float* Y = (float*)d_out;

  // workspace layout
  size_t off = 0;
  char*  qx = (char*)d_ws;            off += (size_t)M_DIM * K_DIM;      // 33.5 MB
  char*  qw = (char*)d_ws + off;      off += (size_t)N_DIM * K_DIM;      // 16.8 MB
  char*  qR = (char*)d_ws + off;      off += (size_t)M_DIM * 64;
  char*  qo = (char*)d_ws + off;      off += (size_t)N_DIM * 64;
  float* sx = (float*)((char*)d_ws + off); off += (size_t)M_DIM * 4;
  float* sR = (float*)((char*)d_ws + off); off += (size_t)M_DIM * 4;
  float* so = (float*)((char*)d_ws + off); off += (size_t)N_DIM * 4;
  float* ST = (float*)((char*)d_ws + off); off += (size_t)32 * N_DIM * 4;

  if (ws_size >= off) {
    prep<<<dim3(PX_BLOCKS + PW_BLOCKS + PO_BLOCKS), dim3(256), 0, stream>>>(
        X, P, S, Ofs, qx, qw, qR, qo, sx, sR, so, ST);

    hipFuncSetAttribute((const void*)gemm_i8,
                        hipFuncAttributeMaxDynamicSharedMemorySize, 65536);
    dim3 grid(N_DIM / 256, M_DIM / 256);  // (16, 32)
    gemm_i8<<<grid, dim3(512), 65536, stream>>>(qx, qw, ST, sx, sR, so, qR, qo, Bias, Y);
  } else {
    dim3 grid(N_DIM / 128, M_DIM / 128);
    qlin_fused_gemm<<<grid, dim3(256), 0, stream>>>(X, P, S, Ofs, Bias, Y);
  }
}

// Round 12
// 264.412 us; speedup vs baseline: 1.2298x; 1.2298x over previous
//
#include <hip/hip_runtime.h>
#include <stdint.h>

typedef __attribute__((ext_vector_type(4))) float  f32x4;
typedef __attribute__((ext_vector_type(4))) int    i32x4;
typedef __attribute__((ext_vector_type(8))) __bf16 bf16x8;

constexpr int M_DIM = 8192, N_DIM = 4096, K_DIM = 4096;

#define VMCNT(n) asm volatile("s_waitcnt vmcnt(" #n ")" ::: "memory")
#define SB __builtin_amdgcn_sched_barrier(0)

// ---------------- pass 1: fused prep (X cvt + W dequant) -------------------
constexpr int CVT_BLOCKS = (M_DIM * K_DIM) / (256 * 8);   // 16384
constexpr int DEQ_BLOCKS = (N_DIM * K_DIM) / (256 * 32);  // 2048

__global__ __launch_bounds__(256) void prep(const float* __restrict__ X,
                                            const int* __restrict__ P,
                                            const float* __restrict__ S,
                                            const float* __restrict__ O,
                                            __bf16* __restrict__ Xb,
                                            __bf16* __restrict__ Wb) {
  const int b = blockIdx.x;
  if (b < CVT_BLOCKS) {
    size_t i = ((size_t)b * 256 + threadIdx.x) * 8;
    const f32x4* src = (const f32x4*)(X + i);
    f32x4 a = src[0], c = src[1];
    bf16x8 v;
    v[0] = (__bf16)a[0]; v[1] = (__bf16)a[1]; v[2] = (__bf16)a[2]; v[3] = (__bf16)a[3];
    v[4] = (__bf16)c[0]; v[5] = (__bf16)c[1]; v[6] = (__bf16)c[2]; v[7] = (__bf16)c[3];
    *(bf16x8*)(Xb + i) = v;
  } else {
    size_t i = (size_t)(b - CVT_BLOCKS) * 256 + threadIdx.x;  // 32 weights
    const i32x4* src = (const i32x4*)(P + i * 16);
    int g = (int)(i >> 2);
    float s = S[g], o = O[g];
    __bf16* dst = Wb + i * 32;
#pragma unroll
    for (int j = 0; j < 4; ++j) {
      i32x4 p = src[j];
      bf16x8 v;
#pragma unroll
      for (int bb = 0; bb < 4; ++bb) {
        int pv = p[bb];
        v[2 * bb]     = (__bf16)fmaf((float)(pv & 15), s, o);
        v[2 * bb + 1] = (__bf16)fmaf((float)((pv >> 4) & 15), s, o);
      }
      *(bf16x8*)(dst + j * 8) = v;
    }
  }
}

// stage one 64-row x 64-col chunk (8 KiB). LDS dest linear; global source
// col pre-XOR-swizzled (rule #21).
__device__ __forceinline__ void stage64(const char* g, size_t rs, char* l, int tid) {
  const int r = tid >> 3;
  const int c = ((tid & 7) * 16) ^ ((r & 7) << 4);
  __builtin_amdgcn_global_load_lds(
      (const __attribute__((address_space(1))) uint32_t*)(g + (size_t)r * rs + c),
      (__attribute__((address_space(3))) uint32_t*)(l + (tid >> 6) * 1024),
      16, 0, 0);
}

__device__ __forceinline__ void read_a(bf16x8 (&dst)[4], const char* Ab,
                                       int wm, int ln15, int lq, int mh, int ks) {
#pragma unroll
  for (int m4 = 0; m4 < 4; ++m4) {
    const int r = wm * 128 + (mh * 4 + m4) * 16 + ln15;
    const int sw = (r & 7) << 4;
    dst[m4] = *(const bf16x8*)(Ab + r * 128 + ((ks * 64 + lq * 16) ^ sw));
  }
}

__device__ __forceinline__ void read_b(bf16x8 (&dst)[4], const char* Bb,
                                       int wn, int ln15, int lq, int ks) {
#pragma unroll
  for (int n = 0; n < 4; ++n) {
    const int r = wn * 64 + n * 16 + ln15;
    const int sw = (r & 7) << 4;
    dst[n] = *(const bf16x8*)(Bb + r * 128 + ((ks * 64 + lq * 16) ^ sw));
  }
}

__device__ __forceinline__ void mfma16(f32x4 (&acc)[8][4], const bf16x8 (&af)[4],
                                       const bf16x8 (&bf)[4], int mbase) {
  __builtin_amdgcn_s_setprio(1);
#pragma unroll
  for (int m4 = 0; m4 < 4; ++m4)
#pragma unroll
    for (int n = 0; n < 4; ++n)
      acc[mbase + m4][n] = __builtin_amdgcn_mfma_f32_16x16x32_bf16(
          af[m4], bf[n], acc[mbase + m4][n], 0, 0, 0);
  __builtin_amdgcn_s_setprio(0);
}

// -- pass 2: 256x256x64 4-phase GEMM, reads one-phase-ahead, compiler lgkm --
__global__ __launch_bounds__(512, 2) void gemm8(const __bf16* __restrict__ A,
                                                const __bf16* __restrict__ B,
                                                const float* __restrict__ Bias,
                                                float* __restrict__ Y) {
  extern __shared__ char lds[];  // [A b0|A b1|B b0|B b1] = 4 x 32 KiB

  constexpr int NT = K_DIM / 64;
  const int tid  = threadIdx.x;
  const int lane = tid & 63;
  const int wid  = tid >> 6;
  const int wm   = wid >> 2;
  const int wn   = wid & 3;
  const int ln15 = lane & 15;
  const int lq   = lane >> 4;

  // T1: bijective XCD swizzle (nwg = 512, 512 % 8 == 0)
  const int id  = blockIdx.y * gridDim.x + blockIdx.x;
  const int swz = (id & 7) * 64 + (id >> 3);
  const int bn0 = (swz & 15) * 256;
  const int bm0 = (swz >> 4) * 256;

  const size_t rs = (size_t)K_DIM * 2;
  const char* Ag = (const char*)A + (size_t)bm0 * rs;
  const char* Bg = (const char*)B + (size_t)bn0 * rs;

  f32x4 acc[8][4];
#pragma unroll
  for (int m = 0; m < 8; ++m)
#pragma unroll
    for (int n = 0; n < 4; ++n)
      acc[m][n] = (f32x4){0.f, 0.f, 0.f, 0.f};

  bf16x8 af0[4], af1[4], bf0[4], bf1[4];

  // ---- prologue: all 8 chunks of tile 0 + B0,B1 of tile 1 ----
  {
    char* Ab = lds;
    char* Bb = lds + 65536;
    stage64(Bg + (size_t)0 * rs,   rs, Bb + 0,     tid);  // B0(0)
    stage64(Bg + (size_t)64 * rs,  rs, Bb + 8192,  tid);  // B1(0)
    stage64(Bg + (size_t)128 * rs, rs, Bb + 16384, tid);  // B2(0)
    stage64(Bg + (size_t)192 * rs, rs, Bb + 24576, tid);  // B3(0)
    stage64(Ag + (size_t)0 * rs,   rs, Ab + 0,     tid);  // A0(0)
    stage64(Ag + (size_t)64 * rs,  rs, Ab + 8192,  tid);  // A1(0)
    stage64(Ag + (size_t)128 * rs, rs, Ab + 16384, tid);  // A2(0)
    stage64(Ag + (size_t)192 * rs, rs, Ab + 24576, tid);  // A3(0)
    char* Bn = lds + 65536 + 32768;
    stage64(Bg + 128,                   rs, Bn + 0,    tid);   // B0(1)
    stage64(Bg + (size_t)64 * rs + 128, rs, Bn + 8192, tid);   // B1(1)
  }
  VMCNT(2);   // confirm all of tile 0; B0,B1(1) stay in flight
  __builtin_amdgcn_s_barrier();
  SB;
  read_b(bf0, lds + 65536, wn, ln15, lq, 0);
  read_a(af0, lds,         wm, ln15, lq, 0, 0);

  for (int t = 0; t < NT; ++t) {
    const char* Ab = lds + (t & 1) * 32768;
    const char* Bb = lds + 65536 + (t & 1) * 32768;
    char* An  = lds + ((t + 1) & 1) * 32768;
    char* Bn  = lds + 65536 + ((t + 1) & 1) * 32768;
    char* Bn2 = lds + 65536 + (t & 1) * 32768;      // tile t+2 B-buffer
    const bool s1 = (t + 1 < NT);
    const bool s2 = (t + 2 < NT);
    const char* ga1 = Ag + (size_t)(t + 1) * 128;
    const char* gb1 = Bg + (size_t)(t + 1) * 128;
    const char* gb2 = Bg + (size_t)(t + 2) * 128;

    // ---------- q0: MFMA(mh0,ks0); read af1 for q1; stage 3 ----------
    mfma16(acc, af0, bf0, 0);
    if (s1) {
      stage64(gb1 + (size_t)128 * rs, rs, Bn + 16384, tid);  // B2(t+1)
      stage64(gb1 + (size_t)192 * rs, rs, Bn + 24576, tid);  // B3(t+1)
      stage64(ga1,                    rs, An + 0,     tid);  // A0(t+1)
    }
    read_a(af1, Ab, wm, ln15, lq, 1, 0);   // tile-t data, confirmed last tile
    SB;
    __builtin_amdgcn_s_barrier();
    SB;

    // ---------- q1: MFMA(mh1,ks0); read bf1,af0(ks1); stage 3 ----------
    mfma16(acc, af1, bf0, 4);
    if (s1) {
      stage64(ga1 + (size_t)128 * rs, rs, An + 16384, tid);  // A2(t+1)
      stage64(ga1 + (size_t)64 * rs,  rs, An + 8192,  tid);  // A1(t+1)
      stage64(ga1 + (size_t)192 * rs, rs, An + 24576, tid);  // A3(t+1)
    }
    read_b(bf1, Bb, wn, ln15, lq, 1);
    read_a(af0, Ab, wm, ln15, lq, 0, 1);
    SB;
    __builtin_amdgcn_s_barrier();
    SB;

    // ---------- q2: MFMA(mh0,ks1); read af1(ks1) ----------
    mfma16(acc, af0, bf1, 0);
    read_a(af1, Ab, wm, ln15, lq, 1, 1);
    SB;
    __builtin_amdgcn_s_barrier();
    SB;

    // ---------- q3: MFMA(mh1,ks1); stage B0,B1(t+2); confirm t+1 ----------
    mfma16(acc, af1, bf1, 4);
    if (s1) {
      if (s2) {
        stage64(gb2,                   rs, Bn2 + 0,    tid);  // B0(t+2)
        stage64(gb2 + (size_t)64 * rs, rs, Bn2 + 8192, tid);  // B1(t+2)
        VMCNT(2);      // confirm ALL of t+1; B0,B1(t+2) stay in flight
      } else {
        VMCNT(0);      // second-to-last tile: drain
      }
      __builtin_amdgcn_s_barrier();
      SB;
      read_b(bf0, Bn, wn, ln15, lq, 0);   // fresh t+1 data (only exposed reads)
      read_a(af0, An, wm, ln15, lq, 0, 0);
      SB;
    }
  }

  // ---- epilogue: bias + fp32 store. C/D: col=lane&15, row=(lane>>4)*4+reg ----
#pragma unroll
  for (int n = 0; n < 4; ++n) {
    const int col = bn0 + wn * 64 + n * 16 + ln15;
    const float bias = Bias[col];
#pragma unroll
    for (int m = 0; m < 8; ++m) {
      const int row0 = bm0 + wm * 128 + m * 16 + lq * 4;
#pragma unroll
      for (int r = 0; r < 4; ++r)
        Y[(size_t)(row0 + r) * N_DIM + col] = acc[m][n][r] + bias;
    }
  }
}

// ------------------- fallback: round-0 fused kernel ------------------------
__global__ __launch_bounds__(256) void qlin_fused_gemm(
    const float* __restrict__ X, const int* __restrict__ P,
    const float* __restrict__ S, const float* __restrict__ Ofs,
    const float* __restrict__ Bias, float* __restrict__ Y)
{
  constexpr int BM = 128, BN = 128, BK = 64;
  constexpr int NT = K_DIM / BK;
  __shared__ __bf16 As[BM * BK];
  __shared__ __bf16 Bs[BN * BK];

  const int tid  = threadIdx.x;
  const int lane = tid & 63;
  const int wv   = tid >> 6;
  const int wr   = (wv >> 1) * 64;
  const int wc   = (wv & 1) * 64;
  const int bn0 = blockIdx.x * BN;
  const int bm0 = blockIdx.y * BM;
  const int srow  = tid >> 1;
  const int shalf = tid & 1;

  const float* xrow = X + (size_t)(bm0 + srow) * K_DIM + shalf * 32;
  const int*   prow = P + (size_t)(bn0 + srow) * (K_DIM / 2) + shalf * 16;
  const int    gbase = (bn0 + srow) * (K_DIM / 128);

  const int rowb = srow * (BK * 2);
  const int sxor = (srow & 7) << 4;
  const int cbb  = shalf * 64;

  f32x4 areg[8];
  i32x4 breg[4];
  float sc, of;

  f32x4 acc[4][4];
#pragma unroll
  for (int i = 0; i < 4; ++i)
#pragma unroll
    for (int j = 0; j < 4; ++j)
      acc[i][j] = (f32x4){0.f, 0.f, 0.f, 0.f};

#pragma unroll
  for (int i = 0; i < 8; ++i) areg[i] = *(const f32x4*)(xrow + 4 * i);
#pragma unroll
  for (int i = 0; i < 4; ++i) breg[i] = *(const i32x4*)(prow + 4 * i);
  sc = S[gbase];
  of = Ofs[gbase];

  for (int kt = 0; kt < NT; ++kt) {
    __syncthreads();
    {
      char* ab = (char*)As + rowb;
      char* bb = (char*)Bs + rowb;
#pragma unroll
      for (int i = 0; i < 4; ++i) {
        bf16x8 v;
        f32x4 u0 = areg[2 * i], u1 = areg[2 * i + 1];
        v[0] = (__bf16)u0[0]; v[1] = (__bf16)u0[1];
        v[2] = (__bf16)u0[2]; v[3] = (__bf16)u0[3];
        v[4] = (__bf16)u1[0]; v[5] = (__bf16)u1[1];
        v[6] = (__bf16)u1[2]; v[7] = (__bf16)u1[3];
        *(bf16x8*)(ab + ((cbb + 16 * i) ^ sxor)) = v;
      }
#pragma unroll
      for (int i = 0; i < 4; ++i) {
        bf16x8 v;
        i32x4 p = breg[i];
#pragma unroll
        for (int j = 0; j < 4; ++j) {
          int pv = p[j];
          v[2 * j]     = (__bf16)fmaf((float)(pv & 15), sc, of);
          v[2 * j + 1] = (__bf16)fmaf((float)((pv >> 4) & 15), sc, of);
        }
        *(bf16x8*)(bb + ((cbb + 16 * i) ^ sxor)) = v;
      }
    }
    if (kt + 1 < NT) {
      const float* xp = xrow + (kt + 1) * BK;
#pragma unroll
      for (int i = 0; i < 8; ++i) areg[i] = *(const f32x4*)(xp + 4 * i);
      const int* pp = prow + (kt + 1) * (BK / 2);
#pragma unroll
      for (int i = 0; i < 4; ++i) breg[i] = *(const i32x4*)(pp + 4 * i);
      int g = gbase + (kt + 1) / 2;
      sc = S[g]; of = Ofs[g];
    }
    __syncthreads();
#pragma unroll
    for (int ks = 0; ks < 2; ++ks) {
      const int cb = ks * 64 + (lane >> 4) * 16;
      bf16x8 afr[4], bfr[4];
#pragma unroll
      for (int m = 0; m < 4; ++m) {
        int r = wr + m * 16 + (lane & 15);
        afr[m] = *(const bf16x8*)((const char*)As + r * (BK * 2) + (cb ^ ((r & 7) << 4)));
      }
#pragma unroll
      for (int n = 0; n < 4; ++n) {
        int r = wc + n * 16 + (lane & 15);
        bfr[n] = *(const bf16x8*)((const char*)Bs + r * (BK * 2) + (cb ^ ((r & 7) << 4)));
      }
#pragma unroll
      for (int m = 0; m < 4; ++m)
#pragma unroll
        for (int n = 0; n < 4; ++n)
          acc[m][n] = __builtin_amdgcn_mfma_f32_16x16x32_bf16(afr[m], bfr[n], acc[m][n], 0, 0, 0);
    }
  }
#pragma unroll
  for (int n = 0; n < 4; ++n) {
    const int col = bn0 + wc + n * 16 + (lane & 15);
    const float bias = Bias[col];
#pragma unroll
    for (int m = 0; m < 4; ++m) {
      const int row0 = bm0 + wr + m * 16 + (lane >> 4) * 4;
#pragma unroll
      for (int r = 0; r < 4; ++r)
        Y[(size_t)(row0 + r) * N_DIM + col] = acc[m][n][r] + bias;
    }
  }
}

extern "C" void kernel_launch(void* const* d_in, const int* in_sizes, int n_in,
                              void* d_out, int out_size, void* d_ws, size_t ws_size,
                              hipStream_t stream) {
  const float* X    = (const float*)d_in[0];
  const int*   P    = (const int*)d_in[1];
  const float* S    = (const float*)d_in[2];
  const float* Ofs  = (const float*)d_in[3];
  const float* Bias = (const float*)d_in[4];
  float* Y = (float*)d_out;

  const size_t xb_bytes = (size_t)M_DIM * K_DIM * 2;
  const size_t wb_bytes = (size_t)N_DIM * K_DIM * 2;

  if (ws_size >= xb_bytes + wb_bytes) {
    __bf16* Xb = (__bf16*)d_ws;
    __bf16* Wb = (__bf16*)((char*)d_ws + xb_bytes);

    prep<<<dim3(CVT_BLOCKS + DEQ_BLOCKS), dim3(256), 0, stream>>>(X, P, S, Ofs, Xb, Wb);

    hipFuncSetAttribute((const void*)gemm8,
                        hipFuncAttributeMaxDynamicSharedMemorySize, 131072);
    dim3 grid(N_DIM / 256, M_DIM / 256);  // (16, 32)
    gemm8<<<grid, dim3(512), 131072, stream>>>(Xb, Wb, Bias, Y);
  } else {
    dim3 grid(N_DIM / 128, M_DIM / 128);
    qlin_fused_gemm<<<grid, dim3(256), 0, stream>>>(X, P, S, Ofs, Bias, Y);
  }
}